// Round 7
// baseline (1485.410 us; speedup 1.0000x reference)
//
#include <hip/hip_runtime.h>
#include <hip/hip_bf16.h>

#define NUSERS 100000
#define NITEMS 50000
#define NN 150000            // total nodes
#define DD 64                // hidden dim
#define DE 16                // eigs dim
#define NLAYERS 2
#define NE 1500000           // edges per layer
#define NPATH 14
#define LN_EPS 1e-5f

#define BROWS 512            // rows per bucket
#define BCAP 8192            // edge capacity per bucket (avg 5120, +42 sigma)
#define NBL 293              // ceil(NN/BROWS)
#define NB (2 * NBL)         // both layers

__device__ __forceinline__ float blo(unsigned u) {
    union { unsigned q; float f; } v; v.q = u << 16; return v.f;
}
__device__ __forceinline__ float bhi(unsigned u) {
    union { unsigned q; float f; } v; v.q = u & 0xffff0000u; return v.f;
}

// ------- layernorm rows -> y (bf16); acc = (+=) x (for final mean) ----
// first=1: source is concat(uemb,iemb), acc = v.  else: source x, acc += v.
__global__ void k_ln(const float* __restrict__ uemb,
                     const float* __restrict__ iemb,
                     const float* __restrict__ xin,
                     float* __restrict__ acc,
                     unsigned short* __restrict__ y,
                     int first) {
    int row = blockIdx.x * 4 + (threadIdx.x >> 6);
    int lane = threadIdx.x & 63;
    if (row >= NN) return;
    int i = row * DD + lane;
    float v;
    if (first) {
        v = (row < NUSERS) ? uemb[i] : iemb[i - NUSERS * DD];
        acc[i] = v;
    } else {
        v = xin[i];
        acc[i] += v;
    }
    float s = v;
    #pragma unroll
    for (int m = 32; m; m >>= 1) s += __shfl_xor(s, m, 64);
    float mu = s * (1.0f / 64.0f);
    float d = v - mu;
    float q = d * d;
    #pragma unroll
    for (int m = 32; m; m >>= 1) q += __shfl_xor(q, m, 64);
    float var = q * (1.0f / 64.0f);
    float yn = d * rsqrtf(var + LN_EPS);
    __hip_bfloat16 h = __float2bfloat16(yn);
    y[i] = *reinterpret_cast<unsigned short*>(&h);
}

// ------- bucket fill: both layers, packed record into bucket frontier -
// record = col | pt<<18 | row_local<<22   (18+4+9 = 31 bits)
__global__ void k_bfill(const int* __restrict__ idx, const int* __restrict__ ptyp,
                        int* __restrict__ cnt, unsigned int* __restrict__ stage) {
    int e = blockIdx.x * 256 + threadIdx.x;
    if (e >= 2 * NE) return;
    int layer = (e >= NE) ? 1 : 0;
    int el = e - layer * NE;
    int r = idx[layer * 2 * NE + el];
    int c = idx[layer * 2 * NE + NE + el];
    int p = ptyp[e];
    int b = layer * NBL + (r >> 9);
    int pos = atomicAdd(cnt + b, 1);
    if (pos < BCAP)
        stage[(size_t)b * BCAP + pos] =
            (unsigned)c | ((unsigned)p << 18) | ((unsigned)(r & 511) << 22);
}

// ------- bucket scatter: LDS hist + scan -> roff + csv (bucket-local) -
__global__ __launch_bounds__(1024) void k_bscatter(
        const unsigned int* __restrict__ stage,
        const int* __restrict__ cnt,
        int* __restrict__ csv,
        int2* __restrict__ roff) {
    __shared__ int scnt[BROWS];
    __shared__ int scur[BROWS];
    int b = blockIdx.x;
    int t = threadIdx.x;
    int layer = b / NBL;
    int brow0 = (b - layer * NBL) * BROWS;
    int nrows = min(BROWS, NN - brow0);
    int n = min(cnt[b], BCAP);
    int base = b * BCAP;
    if (t < BROWS) scnt[t] = 0;
    __syncthreads();
    for (int p = t; p < n; p += 1024)
        atomicAdd(&scnt[stage[base + p] >> 22], 1);
    __syncthreads();
    int orig = (t < BROWS) ? scnt[t] : 0;
    #pragma unroll
    for (int d = 1; d < BROWS; d <<= 1) {
        int a = 0;
        if (t < BROWS && t >= d) a = scnt[t - d];
        __syncthreads();
        if (t < BROWS) scnt[t] += a;
        __syncthreads();
    }
    if (t < BROWS) {
        int excl = scnt[t] - orig;     // exclusive prefix
        scur[t] = excl;
        if (t < nrows)
            roff[(size_t)layer * NN + brow0 + t] =
                make_int2(base + excl, base + excl + orig);
    }
    __syncthreads();
    for (int p = t; p < n; p += 1024) {
        unsigned int rec = stage[base + p];
        int pos = atomicAdd(&scur[rec >> 22], 1);
        csv[base + pos] = (int)(rec & 0x3fffffu);
    }
}

// ---- fused per-row: scores + dual softmax + SpMM (+optional final) ---
// wave per row; 8 edge slots x 8 dim-lanes.  On last layer (accin!=0):
// out = (accin + x2) / 3.
__global__ void k_row(const unsigned short* __restrict__ y,
                      const float* __restrict__ eigs,
                      const int2* __restrict__ roff,
                      const int* __restrict__ csv,
                      const float* __restrict__ pw,   // [L, NPATH]
                      const float* __restrict__ lam,  // [L]
                      int layer,
                      const float* __restrict__ accin,
                      float* __restrict__ xout) {
    __shared__ float pexp[NPATH];
    __shared__ float selam;
    int t = threadIdx.x;
    if (t < NPATH) pexp[t] = fminf(expf(pw[layer * NPATH + t]), 5.0f);
    if (t == NPATH) selam = expf(lam[layer]);
    __syncthreads();

    int row = blockIdx.x * 4 + (t >> 6);     // NN % 4 == 0
    int lane = t & 63;
    int g = lane >> 3;                        // edge slot 0..7
    int sl = lane & 7;                        // dim group: dims 8sl..8sl+7
    int2 pr = roff[row];
    int p0 = pr.x, p1 = pr.y;

    uint4 ar = reinterpret_cast<const uint4*>(y + (size_t)row * DD)[sl];
    float a0 = blo(ar.x), a1 = bhi(ar.x), a2 = blo(ar.y), a3 = bhi(ar.y);
    float a4 = blo(ar.z), a5 = bhi(ar.z), a6 = blo(ar.w), a7 = bhi(ar.w);
    float2 er = reinterpret_cast<const float2*>(eigs + (size_t)row * DE)[sl];
    float elam = selam;

    float sum0 = 0.f, sum1 = 0.f;
    float A0=0,A1=0,A2=0,A3=0,A4=0,A5=0,A6=0,A7=0;
    float B0=0,B1=0,B2=0,B3=0,B4=0,B5=0,B6=0,B7=0;

    for (int p = p0; p < p1; p += 8) {
        int q = p + g;
        bool ok = q < p1;
        int rec = 0;
        uint4 bv = make_uint4(0u, 0u, 0u, 0u);
        float2 ec = make_float2(0.f, 0.f);
        if (ok) {
            rec = csv[q];
            int c = rec & 0x3ffff;
            bv = reinterpret_cast<const uint4*>(y + (size_t)c * DD)[sl];
            ec = reinterpret_cast<const float2*>(eigs + (size_t)c * DE)[sl];
        }
        float b0 = blo(bv.x), b1 = bhi(bv.x), b2 = blo(bv.y), b3 = bhi(bv.y);
        float b4 = blo(bv.z), b5 = bhi(bv.z), b6 = blo(bv.w), b7 = bhi(bv.w);
        float px = a0*b0 + a1*b1 + a2*b2 + a3*b3
                 + a4*b4 + a5*b5 + a6*b6 + a7*b7;
        float pv = er.x * ec.x + er.y * ec.y;
        float sc = px * 0.125f + elam * pv;    // linear: one combined reduce
        sc += __shfl_xor(sc, 4, 64);
        sc += __shfl_xor(sc, 2, 64);
        sc += __shfl_xor(sc, 1, 64);
        float e0 = ok ? fminf(expf(sc), 5.0f) : 0.f;
        float e1 = ok ? pexp[(rec >> 18) & 0xF] : 0.f;
        sum0 += e0; sum1 += e1;
        A0 += e0*b0; A1 += e0*b1; A2 += e0*b2; A3 += e0*b3;
        A4 += e0*b4; A5 += e0*b5; A6 += e0*b6; A7 += e0*b7;
        B0 += e1*b0; B1 += e1*b1; B2 += e1*b2; B3 += e1*b3;
        B4 += e1*b4; B5 += e1*b5; B6 += e1*b6; B7 += e1*b7;
    }

    #pragma unroll
    for (int m = 8; m <= 32; m <<= 1) {
        sum0 += __shfl_xor(sum0, m, 64);
        sum1 += __shfl_xor(sum1, m, 64);
    }
    float rinv0 = 0.5f / ((sum0 == 0.f) ? 1.f : sum0);
    float rinv1 = 0.5f / ((sum1 == 0.f) ? 1.f : sum1);

    float o0 = rinv0*A0 + rinv1*B0, o1 = rinv0*A1 + rinv1*B1;
    float o2 = rinv0*A2 + rinv1*B2, o3 = rinv0*A3 + rinv1*B3;
    float o4 = rinv0*A4 + rinv1*B4, o5 = rinv0*A5 + rinv1*B5;
    float o6 = rinv0*A6 + rinv1*B6, o7 = rinv0*A7 + rinv1*B7;
    #pragma unroll
    for (int m = 8; m <= 32; m <<= 1) {
        o0 += __shfl_xor(o0, m, 64); o1 += __shfl_xor(o1, m, 64);
        o2 += __shfl_xor(o2, m, 64); o3 += __shfl_xor(o3, m, 64);
        o4 += __shfl_xor(o4, m, 64); o5 += __shfl_xor(o5, m, 64);
        o6 += __shfl_xor(o6, m, 64); o7 += __shfl_xor(o7, m, 64);
    }
    if (g == 0) {
        float* dst = xout + (size_t)row * DD + sl * 8;
        if (accin) {
            const float* ap = accin + (size_t)row * DD + sl * 8;
            o0 = (o0 + ap[0]) * (1.f/3.f); o1 = (o1 + ap[1]) * (1.f/3.f);
            o2 = (o2 + ap[2]) * (1.f/3.f); o3 = (o3 + ap[3]) * (1.f/3.f);
            o4 = (o4 + ap[4]) * (1.f/3.f); o5 = (o5 + ap[5]) * (1.f/3.f);
            o6 = (o6 + ap[6]) * (1.f/3.f); o7 = (o7 + ap[7]) * (1.f/3.f);
        }
        reinterpret_cast<float4*>(dst)[0] = make_float4(o0, o1, o2, o3);
        reinterpret_cast<float4*>(dst)[1] = make_float4(o4, o5, o6, o7);
    }
}

extern "C" void kernel_launch(void* const* d_in, const int* in_sizes, int n_in,
                              void* d_out, int out_size, void* d_ws, size_t ws_size,
                              hipStream_t stream) {
    const float* uemb = (const float*)d_in[0];
    const float* iemb = (const float*)d_in[1];
    const float* eigs = (const float*)d_in[2];
    const float* lam  = (const float*)d_in[3];
    const float* pw   = (const float*)d_in[4];
    const int* idx    = (const int*)d_in[5];   // [L, 2, E]
    const int* ptyp   = (const int*)d_in[6];   // [L, E]

    char* w = (char*)d_ws;
    float*          acc   = (float*)(w);                       // 38,400,000
    unsigned int*   stage = (unsigned int*)(w);                // overlays acc (dead before k_ln)
    float*          x     = (float*)(w + 38400000);            // 38,400,000
    unsigned short* y     = (unsigned short*)(w + 76800000);   // 19,200,000
    int*            csv   = (int*)(w + 96000000);              // NB*BCAP*4 = 19,202,048
    int2*           roff  = (int2*)(w + 115202048);            // 2*NN*8 = 2,400,000
    int*            cnt   = (int*)(w + 117602048);             // NB*4 = 2,344
    // total ~117.6 MB

    const int gRows = NN / 4;                    // 37,500
    const int gEdge2 = (2 * NE + 255) / 256;     // 11,719

    // CSR build for both layers (stage overlays acc; acc written later by k_ln)
    hipMemsetAsync(cnt, 0, (size_t)NB * 4, stream);
    k_bfill<<<gEdge2, 256, 0, stream>>>(idx, ptyp, cnt, stage);
    k_bscatter<<<NB, 1024, 0, stream>>>(stage, cnt, csv, roff);

    // layer 0: LN reads embeddings directly, acc = x0
    k_ln<<<gRows, 256, 0, stream>>>(uemb, iemb, nullptr, acc, y, 1);
    k_row<<<gRows, 256, 0, stream>>>(y, eigs, roff, csv, pw, lam, 0,
                                     nullptr, x);
    // layer 1: LN on x1, acc += x1; k_row writes final output
    k_ln<<<gRows, 256, 0, stream>>>(nullptr, nullptr, x, acc, y, 0);
    k_row<<<gRows, 256, 0, stream>>>(y, eigs, roff + NN, csv, pw, lam, 1,
                                     acc, (float*)d_out);
}

// Round 8
// 442.518 us; speedup vs baseline: 3.3567x; 3.3567x over previous
//
#include <hip/hip_runtime.h>
#include <hip/hip_bf16.h>

#define NUSERS 100000
#define NITEMS 50000
#define NN 150000            // total nodes
#define DD 64                // hidden dim
#define DE 16                // eigs dim
#define NLAYERS 2
#define NE 1500000           // edges per layer
#define NPATH 14
#define LN_EPS 1e-5f

#define BROWS 512            // rows per bucket
#define NBUK 293             // buckets per layer = ceil(NN/BROWS)
#define NB (2 * NBUK)        // both layers = 586
#define CHUNK 4096           // edges per partition block
#define NCHUNK ((NE + CHUNK - 1) / CHUNK)        // 367
#define LEN (2 * NBUK * NCHUNK)                  // 215,062
#define SCAN_BLK 1024
#define NSCB ((LEN + SCAN_BLK - 1) / SCAN_BLK)   // 211

__device__ __forceinline__ float blo(unsigned u) {
    union { unsigned q; float f; } v; v.q = u << 16; return v.f;
}
__device__ __forceinline__ float bhi(unsigned u) {
    union { unsigned q; float f; } v; v.q = u & 0xffff0000u; return v.f;
}

// ------- layernorm rows -> y (bf16); acc = (+=) x (for final mean) ----
__global__ void k_ln(const float* __restrict__ uemb,
                     const float* __restrict__ iemb,
                     const float* __restrict__ xin,
                     float* __restrict__ acc,
                     unsigned short* __restrict__ y,
                     int first) {
    int row = blockIdx.x * 4 + (threadIdx.x >> 6);
    int lane = threadIdx.x & 63;
    if (row >= NN) return;
    int i = row * DD + lane;
    float v;
    if (first) {
        v = (row < NUSERS) ? uemb[i] : iemb[i - NUSERS * DD];
        acc[i] = v;
    } else {
        v = xin[i];
        acc[i] += v;
    }
    float s = v;
    #pragma unroll
    for (int m = 32; m; m >>= 1) s += __shfl_xor(s, m, 64);
    float mu = s * (1.0f / 64.0f);
    float d = v - mu;
    float q = d * d;
    #pragma unroll
    for (int m = 32; m; m >>= 1) q += __shfl_xor(q, m, 64);
    float var = q * (1.0f / 64.0f);
    float yn = d * rsqrtf(var + LN_EPS);
    __hip_bfloat16 h = __float2bfloat16(yn);
    y[i] = *reinterpret_cast<unsigned short*>(&h);
}

// ------- partition pass 1: per-(chunk,bucket) counts (LDS hist) -------
__global__ void k_pcount(const int* __restrict__ idx, int* __restrict__ cntmat) {
    int blk = blockIdx.x;                 // 0 .. 2*NCHUNK-1
    int layer = blk / NCHUNK;
    int k = blk - layer * NCHUNK;
    __shared__ int h[NBUK];
    for (int t = threadIdx.x; t < NBUK; t += 256) h[t] = 0;
    __syncthreads();
    const int* rrow = idx + (size_t)layer * 2 * NE;
    int base = k * CHUNK;
    int lim = min(CHUNK, NE - base);
    for (int j = threadIdx.x; j < lim; j += 256)
        atomicAdd(&h[rrow[base + j] >> 9], 1);
    __syncthreads();
    for (int t = threadIdx.x; t < NBUK; t += 256)
        cntmat[((size_t)layer * NBUK + t) * NCHUNK + k] = h[t];
}

// ------- scan pass 1: per-block exclusive scan ------------------------
__global__ __launch_bounds__(SCAN_BLK) void k_scan1(
        const int* __restrict__ cnt, int* __restrict__ off,
        int* __restrict__ bsum, int n) {
    __shared__ int sm[SCAN_BLK];
    int t = threadIdx.x;
    int i = blockIdx.x * SCAN_BLK + t;
    int v = (i < n) ? cnt[i] : 0;
    sm[t] = v;
    __syncthreads();
    #pragma unroll
    for (int d = 1; d < SCAN_BLK; d <<= 1) {
        int a = (t >= d) ? sm[t - d] : 0;
        __syncthreads();
        sm[t] += a;
        __syncthreads();
    }
    if (i < n) off[i] = sm[t] - v;
    if (t == SCAN_BLK - 1) bsum[blockIdx.x] = sm[t];
}

// ------- scan pass 2: scan block sums (nb <= 256) ---------------------
__global__ void k_scan2(int* __restrict__ bsum, int nb) {
    __shared__ int sm[256];
    int t = threadIdx.x;
    int v = (t < nb) ? bsum[t] : 0;
    sm[t] = v;
    __syncthreads();
    #pragma unroll
    for (int d = 1; d < 256; d <<= 1) {
        int a = (t >= d) ? sm[t - d] : 0;
        __syncthreads();
        sm[t] += a;
        __syncthreads();
    }
    if (t < nb) bsum[t] = sm[t] - v;
}

// ------- scan pass 3: add block offsets; emit bucket starts -----------
__global__ __launch_bounds__(SCAN_BLK) void k_scan3(
        int* __restrict__ off, const int* __restrict__ bsum,
        int* __restrict__ bstart, int n) {
    int i = blockIdx.x * SCAN_BLK + threadIdx.x;
    if (i == 0) bstart[NB] = 2 * NE;
    if (i >= n) return;
    int v = off[i] + bsum[blockIdx.x];
    off[i] = v;
    if (i % NCHUNK == 0) bstart[i / NCHUNK] = v;
}

// ------- partition pass 2: scatter records to exact dense slots -------
// record = col | pt<<18 | row_local<<22
__global__ void k_pscatter(const int* __restrict__ idx,
                           const int* __restrict__ ptyp,
                           const int* __restrict__ exsc,
                           unsigned int* __restrict__ stage) {
    int blk = blockIdx.x;
    int layer = blk / NCHUNK;
    int k = blk - layer * NCHUNK;
    __shared__ int hofs[NBUK];
    for (int t = threadIdx.x; t < NBUK; t += 256)
        hofs[t] = exsc[((size_t)layer * NBUK + t) * NCHUNK + k];
    __syncthreads();
    const int* rrow = idx + (size_t)layer * 2 * NE;
    const int* ccol = rrow + NE;
    const int* pp   = ptyp + (size_t)layer * NE;
    int base = k * CHUNK;
    int lim = min(CHUNK, NE - base);
    for (int j = threadIdx.x; j < lim; j += 256) {
        int e = base + j;
        int r = rrow[e];
        int pos = atomicAdd(&hofs[r >> 9], 1);
        stage[pos] = (unsigned)ccol[e] | ((unsigned)pp[e] << 18)
                   | ((unsigned)(r & 511) << 22);
    }
}

// ------- bucket scatter: LDS hist + scan -> roff + csv ----------------
__global__ __launch_bounds__(1024) void k_bscatter(
        const unsigned int* __restrict__ stage,
        const int* __restrict__ bstart,
        int* __restrict__ csv,
        int2* __restrict__ roff) {
    __shared__ int scnt[BROWS];
    __shared__ int scur[BROWS];
    int b = blockIdx.x;
    int t = threadIdx.x;
    int layer = b / NBUK;
    int brow0 = (b - layer * NBUK) * BROWS;
    int nrows = min(BROWS, NN - brow0);
    int start = bstart[b];
    int n = bstart[b + 1] - start;
    if (t < BROWS) scnt[t] = 0;
    __syncthreads();
    for (int p = t; p < n; p += 1024)
        atomicAdd(&scnt[stage[start + p] >> 22], 1);
    __syncthreads();
    int orig = (t < BROWS) ? scnt[t] : 0;
    #pragma unroll
    for (int d = 1; d < BROWS; d <<= 1) {
        int a = 0;
        if (t < BROWS && t >= d) a = scnt[t - d];
        __syncthreads();
        if (t < BROWS) scnt[t] += a;
        __syncthreads();
    }
    if (t < BROWS) {
        int excl = scnt[t] - orig;
        scur[t] = excl;
        if (t < nrows)
            roff[(size_t)layer * NN + brow0 + t] =
                make_int2(start + excl, start + excl + orig);
    }
    __syncthreads();
    for (int p = t; p < n; p += 1024) {
        unsigned rec = stage[start + p];
        int pos = atomicAdd(&scur[rec >> 22], 1);
        csv[start + pos] = (int)(rec & 0x3fffffu);
    }
}

// ---- fused per-row: scores + dual softmax + SpMM (+optional final) ---
__global__ void k_row(const unsigned short* __restrict__ y,
                      const float* __restrict__ eigs,
                      const int2* __restrict__ roff,
                      const int* __restrict__ csv,
                      const float* __restrict__ pw,   // [L, NPATH]
                      const float* __restrict__ lam,  // [L]
                      int layer,
                      const float* __restrict__ accin,
                      float* __restrict__ xout) {
    __shared__ float pexp[NPATH];
    __shared__ float selam;
    int t = threadIdx.x;
    if (t < NPATH) pexp[t] = fminf(expf(pw[layer * NPATH + t]), 5.0f);
    if (t == NPATH) selam = expf(lam[layer]);
    __syncthreads();

    int row = blockIdx.x * 4 + (t >> 6);     // NN % 4 == 0
    int lane = t & 63;
    int g = lane >> 3;                        // edge slot 0..7
    int sl = lane & 7;                        // dim group: dims 8sl..8sl+7
    int2 pr = roff[row];
    int p0 = pr.x, p1 = pr.y;

    uint4 ar = reinterpret_cast<const uint4*>(y + (size_t)row * DD)[sl];
    float a0 = blo(ar.x), a1 = bhi(ar.x), a2 = blo(ar.y), a3 = bhi(ar.y);
    float a4 = blo(ar.z), a5 = bhi(ar.z), a6 = blo(ar.w), a7 = bhi(ar.w);
    float2 er = reinterpret_cast<const float2*>(eigs + (size_t)row * DE)[sl];
    float elam = selam;

    float sum0 = 0.f, sum1 = 0.f;
    float A0=0,A1=0,A2=0,A3=0,A4=0,A5=0,A6=0,A7=0;
    float B0=0,B1=0,B2=0,B3=0,B4=0,B5=0,B6=0,B7=0;

    for (int p = p0; p < p1; p += 8) {
        int q = p + g;
        bool ok = q < p1;
        int rec = 0;
        uint4 bv = make_uint4(0u, 0u, 0u, 0u);
        float2 ec = make_float2(0.f, 0.f);
        if (ok) {
            rec = csv[q];
            int c = rec & 0x3ffff;
            bv = reinterpret_cast<const uint4*>(y + (size_t)c * DD)[sl];
            ec = reinterpret_cast<const float2*>(eigs + (size_t)c * DE)[sl];
        }
        float b0 = blo(bv.x), b1 = bhi(bv.x), b2 = blo(bv.y), b3 = bhi(bv.y);
        float b4 = blo(bv.z), b5 = bhi(bv.z), b6 = blo(bv.w), b7 = bhi(bv.w);
        float px = a0*b0 + a1*b1 + a2*b2 + a3*b3
                 + a4*b4 + a5*b5 + a6*b6 + a7*b7;
        float pv = er.x * ec.x + er.y * ec.y;
        float sc = px * 0.125f + elam * pv;    // linear: one combined reduce
        sc += __shfl_xor(sc, 4, 64);
        sc += __shfl_xor(sc, 2, 64);
        sc += __shfl_xor(sc, 1, 64);
        float e0 = ok ? fminf(expf(sc), 5.0f) : 0.f;
        float e1 = ok ? pexp[(rec >> 18) & 0xF] : 0.f;
        sum0 += e0; sum1 += e1;
        A0 += e0*b0; A1 += e0*b1; A2 += e0*b2; A3 += e0*b3;
        A4 += e0*b4; A5 += e0*b5; A6 += e0*b6; A7 += e0*b7;
        B0 += e1*b0; B1 += e1*b1; B2 += e1*b2; B3 += e1*b3;
        B4 += e1*b4; B5 += e1*b5; B6 += e1*b6; B7 += e1*b7;
    }

    #pragma unroll
    for (int m = 8; m <= 32; m <<= 1) {
        sum0 += __shfl_xor(sum0, m, 64);
        sum1 += __shfl_xor(sum1, m, 64);
    }
    float rinv0 = 0.5f / ((sum0 == 0.f) ? 1.f : sum0);
    float rinv1 = 0.5f / ((sum1 == 0.f) ? 1.f : sum1);

    float o0 = rinv0*A0 + rinv1*B0, o1 = rinv0*A1 + rinv1*B1;
    float o2 = rinv0*A2 + rinv1*B2, o3 = rinv0*A3 + rinv1*B3;
    float o4 = rinv0*A4 + rinv1*B4, o5 = rinv0*A5 + rinv1*B5;
    float o6 = rinv0*A6 + rinv1*B6, o7 = rinv0*A7 + rinv1*B7;
    #pragma unroll
    for (int m = 8; m <= 32; m <<= 1) {
        o0 += __shfl_xor(o0, m, 64); o1 += __shfl_xor(o1, m, 64);
        o2 += __shfl_xor(o2, m, 64); o3 += __shfl_xor(o3, m, 64);
        o4 += __shfl_xor(o4, m, 64); o5 += __shfl_xor(o5, m, 64);
        o6 += __shfl_xor(o6, m, 64); o7 += __shfl_xor(o7, m, 64);
    }
    if (g == 0) {
        float* dst = xout + (size_t)row * DD + sl * 8;
        if (accin) {
            const float* ap = accin + (size_t)row * DD + sl * 8;
            o0 = (o0 + ap[0]) * (1.f/3.f); o1 = (o1 + ap[1]) * (1.f/3.f);
            o2 = (o2 + ap[2]) * (1.f/3.f); o3 = (o3 + ap[3]) * (1.f/3.f);
            o4 = (o4 + ap[4]) * (1.f/3.f); o5 = (o5 + ap[5]) * (1.f/3.f);
            o6 = (o6 + ap[6]) * (1.f/3.f); o7 = (o7 + ap[7]) * (1.f/3.f);
        }
        reinterpret_cast<float4*>(dst)[0] = make_float4(o0, o1, o2, o3);
        reinterpret_cast<float4*>(dst)[1] = make_float4(o4, o5, o6, o7);
    }
}

extern "C" void kernel_launch(void* const* d_in, const int* in_sizes, int n_in,
                              void* d_out, int out_size, void* d_ws, size_t ws_size,
                              hipStream_t stream) {
    const float* uemb = (const float*)d_in[0];
    const float* iemb = (const float*)d_in[1];
    const float* eigs = (const float*)d_in[2];
    const float* lam  = (const float*)d_in[3];
    const float* pw   = (const float*)d_in[4];
    const int* idx    = (const int*)d_in[5];   // [L, 2, E]
    const int* ptyp   = (const int*)d_in[6];   // [L, E]

    char* w = (char*)d_ws;
    // transient (partition phase) — overlays acc/x region, dead before k_ln:
    unsigned int* stage  = (unsigned int*)(w);                 // 12,000,000
    int*          cnt    = (int*)(w + 12000000);               //    860,248
    int*          off    = (int*)(w + 12860248);               //    860,248
    int*          bsum   = (int*)(w + 13720496);               //        844
    int*          bstart = (int*)(w + 13721344);               //      2,348
    // persistent:
    float*          acc  = (float*)(w);                        // 38,400,000
    float*          x    = (float*)(w + 38400000);             // 38,400,000
    unsigned short* y    = (unsigned short*)(w + 76800000);    // 19,200,000
    int*            csv  = (int*)(w + 96000000);               // 12,000,000
    int2*           roff = (int2*)(w + 108000000);             //  2,400,000
    // total 110,400,000 B

    const int gRows = NN / 4;                    // 37,500

    // deterministic CSR build for both layers (zero global atomics)
    k_pcount<<<2 * NCHUNK, 256, 0, stream>>>(idx, cnt);
    k_scan1<<<NSCB, SCAN_BLK, 0, stream>>>(cnt, off, bsum, LEN);
    k_scan2<<<1, 256, 0, stream>>>(bsum, NSCB);
    k_scan3<<<NSCB, SCAN_BLK, 0, stream>>>(off, bsum, bstart, LEN);
    k_pscatter<<<2 * NCHUNK, 256, 0, stream>>>(idx, ptyp, off, stage);
    k_bscatter<<<NB, 1024, 0, stream>>>(stage, bstart, csv, roff);

    // layer 0: LN reads embeddings directly, acc = x0
    k_ln<<<gRows, 256, 0, stream>>>(uemb, iemb, nullptr, acc, y, 1);
    k_row<<<gRows, 256, 0, stream>>>(y, eigs, roff, csv, pw, lam, 0,
                                     nullptr, x);
    // layer 1: LN on x1, acc += x1; k_row writes final output
    k_ln<<<gRows, 256, 0, stream>>>(nullptr, nullptr, x, acc, y, 0);
    k_row<<<gRows, 256, 0, stream>>>(y, eigs, roff + NN, csv, pw, lam, 1,
                                     acc, (float*)d_out);
}

// Round 9
// 424.878 us; speedup vs baseline: 3.4961x; 1.0415x over previous
//
#include <hip/hip_runtime.h>
#include <hip/hip_bf16.h>

#define NUSERS 100000
#define NITEMS 50000
#define NN 150000            // total nodes
#define DD 64                // hidden dim
#define DE 16                // eigs dim
#define NE 1500000           // edges per layer
#define NPATH 14
#define LN_EPS 1e-5f

#define BROWS 512            // rows per bucket
#define NBUK 293             // buckets per layer = ceil(NN/BROWS)
#define NB (2 * NBUK)        // both layers = 586
#define CHUNK 4096           // edges per partition block
#define NCHUNK ((NE + CHUNK - 1) / CHUNK)        // 367

__device__ __forceinline__ float blo(unsigned u) {
    union { unsigned q; float f; } v; v.q = u << 16; return v.f;
}
__device__ __forceinline__ float bhi(unsigned u) {
    union { unsigned q; float f; } v; v.q = u & 0xffff0000u; return v.f;
}
// f32 -> bf16 bits, round-to-nearest-even
__device__ __forceinline__ unsigned f2b(float f) {
    union { float f; unsigned u; } v; v.f = f;
    return (v.u + 0x7fffu + ((v.u >> 16) & 1u)) >> 16;
}

// ------- eigs f32 -> bf16 ---------------------------------------------
__global__ void k_eig(const float* __restrict__ eigs,
                      unsigned short* __restrict__ e16) {
    int i = blockIdx.x * 256 + threadIdx.x;
    if (i < NN * DE) e16[i] = (unsigned short)f2b(eigs[i]);
}

// ------- layer-0 LN: emb -> y0 (bf16) ---------------------------------
__global__ void k_ln0(const float* __restrict__ uemb,
                      const float* __restrict__ iemb,
                      unsigned short* __restrict__ y) {
    int row = blockIdx.x * 4 + (threadIdx.x >> 6);
    int lane = threadIdx.x & 63;
    if (row >= NN) return;
    int i = row * DD + lane;
    float v = (row < NUSERS) ? uemb[i] : iemb[i - NUSERS * DD];
    float s = v;
    #pragma unroll
    for (int m = 32; m; m >>= 1) s += __shfl_xor(s, m, 64);
    float mu = s * (1.0f / 64.0f);
    float d = v - mu;
    float q = d * d;
    #pragma unroll
    for (int m = 32; m; m >>= 1) q += __shfl_xor(q, m, 64);
    float rs = rsqrtf(q * (1.0f / 64.0f) + LN_EPS);
    y[i] = (unsigned short)f2b(d * rs);
}

// ------- partition pass 1: per-(chunk,bucket) counts (LDS hist) -------
__global__ void k_pcount(const int* __restrict__ idx, int* __restrict__ cntmat) {
    int blk = blockIdx.x;                 // 0 .. 2*NCHUNK-1
    int layer = blk / NCHUNK;
    int k = blk - layer * NCHUNK;
    __shared__ int h[NBUK];
    for (int t = threadIdx.x; t < NBUK; t += 256) h[t] = 0;
    __syncthreads();
    const int* rrow = idx + (size_t)layer * 2 * NE;
    int base = k * CHUNK;
    int lim = min(CHUNK, NE - base);
    for (int j = threadIdx.x; j < lim; j += 256)
        atomicAdd(&h[rrow[base + j] >> 9], 1);
    __syncthreads();
    for (int t = threadIdx.x; t < NBUK; t += 256)
        cntmat[((size_t)layer * NBUK + t) * NCHUNK + k] = h[t];
}

// ------- per-bucket scan over chunks: exsc + bucket totals ------------
__global__ __launch_bounds__(512) void k_bukscan(const int* __restrict__ cnt,
                                                 int* __restrict__ exsc,
                                                 int* __restrict__ tot) {
    __shared__ int sm[512];
    int b = blockIdx.x;                   // 0..NB-1
    int t = threadIdx.x;
    int v = (t < NCHUNK) ? cnt[(size_t)b * NCHUNK + t] : 0;
    sm[t] = v;
    __syncthreads();
    #pragma unroll
    for (int d = 1; d < 512; d <<= 1) {
        int a = (t >= d) ? sm[t - d] : 0;
        __syncthreads();
        sm[t] += a;
        __syncthreads();
    }
    if (t < NCHUNK) exsc[(size_t)b * NCHUNK + t] = sm[t] - v;
    if (t == 511) tot[b] = sm[511];
}

// ------- scan bucket totals -> bstart ---------------------------------
__global__ __launch_bounds__(1024) void k_totscan(const int* __restrict__ tot,
                                                  int* __restrict__ bstart) {
    __shared__ int sm[1024];
    int t = threadIdx.x;
    int v = (t < NB) ? tot[t] : 0;
    sm[t] = v;
    __syncthreads();
    #pragma unroll
    for (int d = 1; d < 1024; d <<= 1) {
        int a = (t >= d) ? sm[t - d] : 0;
        __syncthreads();
        sm[t] += a;
        __syncthreads();
    }
    if (t < NB) bstart[t] = sm[t] - v;
    if (t == 0) bstart[NB] = 2 * NE;
}

// ------- partition pass 2: scatter records to exact dense slots -------
// record = col | pt<<18 | row_local<<22
__global__ void k_pscatter(const int* __restrict__ idx,
                           const int* __restrict__ ptyp,
                           const int* __restrict__ exsc,
                           const int* __restrict__ bstart,
                           unsigned int* __restrict__ stage) {
    int blk = blockIdx.x;
    int layer = blk / NCHUNK;
    int k = blk - layer * NCHUNK;
    __shared__ int hofs[NBUK];
    for (int t = threadIdx.x; t < NBUK; t += 256) {
        int b = layer * NBUK + t;
        hofs[t] = bstart[b] + exsc[(size_t)b * NCHUNK + k];
    }
    __syncthreads();
    const int* rrow = idx + (size_t)layer * 2 * NE;
    const int* ccol = rrow + NE;
    const int* pp   = ptyp + (size_t)layer * NE;
    int base = k * CHUNK;
    int lim = min(CHUNK, NE - base);
    for (int j = threadIdx.x; j < lim; j += 256) {
        int e = base + j;
        int r = rrow[e];
        int pos = atomicAdd(&hofs[r >> 9], 1);
        stage[pos] = (unsigned)ccol[e] | ((unsigned)pp[e] << 18)
                   | ((unsigned)(r & 511) << 22);
    }
}

// ------- bucket scatter: LDS hist + scan -> roff + csv ----------------
__global__ __launch_bounds__(1024) void k_bscatter(
        const unsigned int* __restrict__ stage,
        const int* __restrict__ bstart,
        int* __restrict__ csv,
        int2* __restrict__ roff) {
    __shared__ int scnt[BROWS];
    __shared__ int scur[BROWS];
    int b = blockIdx.x;
    int t = threadIdx.x;
    int layer = b / NBUK;
    int brow0 = (b - layer * NBUK) * BROWS;
    int nrows = min(BROWS, NN - brow0);
    int start = bstart[b];
    int n = bstart[b + 1] - start;
    if (t < BROWS) scnt[t] = 0;
    __syncthreads();
    for (int p = t; p < n; p += 1024)
        atomicAdd(&scnt[stage[start + p] >> 22], 1);
    __syncthreads();
    int orig = (t < BROWS) ? scnt[t] : 0;
    #pragma unroll
    for (int d = 1; d < BROWS; d <<= 1) {
        int a = 0;
        if (t < BROWS && t >= d) a = scnt[t - d];
        __syncthreads();
        if (t < BROWS) scnt[t] += a;
        __syncthreads();
    }
    if (t < BROWS) {
        int excl = scnt[t] - orig;
        scur[t] = excl;
        if (t < nrows)
            roff[(size_t)layer * NN + brow0 + t] =
                make_int2(start + excl, start + excl + orig);
    }
    __syncthreads();
    for (int p = t; p < n; p += 1024) {
        unsigned rec = stage[start + p];
        int pos = atomicAdd(&scur[rec >> 22], 1);
        csv[start + pos] = (int)(rec & 0x3fffffu);
    }
}

// ---- fused per-row: scores + dual softmax + SpMM + fused epilogue ----
// layer 0: write x1 (f32) and y1 = LN(x1) (bf16).
// layer 1: out = (emb + x1 + x2) / 3.
__global__ void k_row(const unsigned short* __restrict__ y,
                      const unsigned short* __restrict__ e16,
                      const int2* __restrict__ roff,
                      const int* __restrict__ csv,
                      const float* __restrict__ pw,   // [L, NPATH]
                      const float* __restrict__ lam,  // [L]
                      int layer,
                      const float* __restrict__ uemb,
                      const float* __restrict__ iemb,
                      float* __restrict__ x1,
                      unsigned short* __restrict__ y1,
                      float* __restrict__ out) {
    __shared__ float pexp[NPATH];
    __shared__ float selam;
    int t = threadIdx.x;
    if (t < NPATH) pexp[t] = fminf(expf(pw[layer * NPATH + t]), 5.0f);
    if (t == NPATH) selam = expf(lam[layer]);
    __syncthreads();

    int row = blockIdx.x * 4 + (t >> 6);     // NN % 4 == 0
    int lane = t & 63;
    int g = lane >> 3;                        // edge slot 0..7
    int sl = lane & 7;                        // dim group: dims 8sl..8sl+7
    int2 pr = roff[row];
    int p0 = pr.x, p1 = pr.y;

    uint4 ar = reinterpret_cast<const uint4*>(y + (size_t)row * DD)[sl];
    float a0 = blo(ar.x), a1 = bhi(ar.x), a2 = blo(ar.y), a3 = bhi(ar.y);
    float a4 = blo(ar.z), a5 = bhi(ar.z), a6 = blo(ar.w), a7 = bhi(ar.w);
    unsigned eru = reinterpret_cast<const unsigned*>(e16 + (size_t)row * DE)[sl];
    float er0 = blo(eru), er1 = bhi(eru);
    float elam = selam;

    float sum0 = 0.f, sum1 = 0.f;
    float A0=0,A1=0,A2=0,A3=0,A4=0,A5=0,A6=0,A7=0;
    float B0=0,B1=0,B2=0,B3=0,B4=0,B5=0,B6=0,B7=0;

    for (int p = p0; p < p1; p += 8) {
        int q = p + g;
        bool ok = q < p1;
        int rec = 0;
        uint4 bv = make_uint4(0u, 0u, 0u, 0u);
        unsigned ecu = 0u;
        if (ok) {
            rec = csv[q];
            int c = rec & 0x3ffff;
            bv = reinterpret_cast<const uint4*>(y + (size_t)c * DD)[sl];
            ecu = reinterpret_cast<const unsigned*>(e16 + (size_t)c * DE)[sl];
        }
        float b0 = blo(bv.x), b1 = bhi(bv.x), b2 = blo(bv.y), b3 = bhi(bv.y);
        float b4 = blo(bv.z), b5 = bhi(bv.z), b6 = blo(bv.w), b7 = bhi(bv.w);
        float px = a0*b0 + a1*b1 + a2*b2 + a3*b3
                 + a4*b4 + a5*b5 + a6*b6 + a7*b7;
        float pv = er0 * blo(ecu) + er1 * bhi(ecu);
        float sc = px * 0.125f + elam * pv;    // linear: one combined reduce
        sc += __shfl_xor(sc, 4, 64);
        sc += __shfl_xor(sc, 2, 64);
        sc += __shfl_xor(sc, 1, 64);
        float e0 = ok ? fminf(expf(sc), 5.0f) : 0.f;
        float e1 = ok ? pexp[(rec >> 18) & 0xF] : 0.f;
        sum0 += e0; sum1 += e1;
        A0 += e0*b0; A1 += e0*b1; A2 += e0*b2; A3 += e0*b3;
        A4 += e0*b4; A5 += e0*b5; A6 += e0*b6; A7 += e0*b7;
        B0 += e1*b0; B1 += e1*b1; B2 += e1*b2; B3 += e1*b3;
        B4 += e1*b4; B5 += e1*b5; B6 += e1*b6; B7 += e1*b7;
    }

    #pragma unroll
    for (int m = 8; m <= 32; m <<= 1) {
        sum0 += __shfl_xor(sum0, m, 64);
        sum1 += __shfl_xor(sum1, m, 64);
    }
    float rinv0 = 0.5f / ((sum0 == 0.f) ? 1.f : sum0);
    float rinv1 = 0.5f / ((sum1 == 0.f) ? 1.f : sum1);

    float o0 = rinv0*A0 + rinv1*B0, o1 = rinv0*A1 + rinv1*B1;
    float o2 = rinv0*A2 + rinv1*B2, o3 = rinv0*A3 + rinv1*B3;
    float o4 = rinv0*A4 + rinv1*B4, o5 = rinv0*A5 + rinv1*B5;
    float o6 = rinv0*A6 + rinv1*B6, o7 = rinv0*A7 + rinv1*B7;
    #pragma unroll
    for (int m = 8; m <= 32; m <<= 1) {
        o0 += __shfl_xor(o0, m, 64); o1 += __shfl_xor(o1, m, 64);
        o2 += __shfl_xor(o2, m, 64); o3 += __shfl_xor(o3, m, 64);
        o4 += __shfl_xor(o4, m, 64); o5 += __shfl_xor(o5, m, 64);
        o6 += __shfl_xor(o6, m, 64); o7 += __shfl_xor(o7, m, 64);
    }
    if (g == 0) {
        int ofs = sl * 8;
        if (layer == 0) {
            float* dst = x1 + (size_t)row * DD + ofs;
            reinterpret_cast<float4*>(dst)[0] = make_float4(o0, o1, o2, o3);
            reinterpret_cast<float4*>(dst)[1] = make_float4(o4, o5, o6, o7);
            // LN of x1 row across 8 lanes x 8 vals -> y1 (bf16)
            float s = o0+o1+o2+o3+o4+o5+o6+o7;
            s += __shfl_xor(s, 1, 64);
            s += __shfl_xor(s, 2, 64);
            s += __shfl_xor(s, 4, 64);
            float mu = s * (1.0f / 64.0f);
            float d0=o0-mu, d1=o1-mu, d2=o2-mu, d3=o3-mu;
            float d4=o4-mu, d5=o5-mu, d6=o6-mu, d7=o7-mu;
            float qv = d0*d0+d1*d1+d2*d2+d3*d3+d4*d4+d5*d5+d6*d6+d7*d7;
            qv += __shfl_xor(qv, 1, 64);
            qv += __shfl_xor(qv, 2, 64);
            qv += __shfl_xor(qv, 4, 64);
            float rs = rsqrtf(qv * (1.0f / 64.0f) + LN_EPS);
            uint4 pk;
            pk.x = f2b(d0*rs) | (f2b(d1*rs) << 16);
            pk.y = f2b(d2*rs) | (f2b(d3*rs) << 16);
            pk.z = f2b(d4*rs) | (f2b(d5*rs) << 16);
            pk.w = f2b(d6*rs) | (f2b(d7*rs) << 16);
            reinterpret_cast<uint4*>(y1 + (size_t)row * DD)[sl] = pk;
        } else {
            const float* e = (row < NUSERS)
                ? (uemb + (size_t)row * DD + ofs)
                : (iemb + (size_t)(row - NUSERS) * DD + ofs);
            const float* xp = x1 + (size_t)row * DD + ofs;
            float4 ea = reinterpret_cast<const float4*>(e)[0];
            float4 eb = reinterpret_cast<const float4*>(e)[1];
            float4 xa = reinterpret_cast<const float4*>(xp)[0];
            float4 xb = reinterpret_cast<const float4*>(xp)[1];
            float* dst = out + (size_t)row * DD + ofs;
            const float k3 = 1.0f / 3.0f;
            reinterpret_cast<float4*>(dst)[0] = make_float4(
                (ea.x + xa.x + o0) * k3, (ea.y + xa.y + o1) * k3,
                (ea.z + xa.z + o2) * k3, (ea.w + xa.w + o3) * k3);
            reinterpret_cast<float4*>(dst)[1] = make_float4(
                (eb.x + xb.x + o4) * k3, (eb.y + xb.y + o5) * k3,
                (eb.z + xb.z + o6) * k3, (eb.w + xb.w + o7) * k3);
        }
    }
}

extern "C" void kernel_launch(void* const* d_in, const int* in_sizes, int n_in,
                              void* d_out, int out_size, void* d_ws, size_t ws_size,
                              hipStream_t stream) {
    const float* uemb = (const float*)d_in[0];
    const float* iemb = (const float*)d_in[1];
    const float* eigs = (const float*)d_in[2];
    const float* lam  = (const float*)d_in[3];
    const float* pw   = (const float*)d_in[4];
    const int* idx    = (const int*)d_in[5];   // [L, 2, E]
    const int* ptyp   = (const int*)d_in[6];   // [L, E]

    char* w = (char*)d_ws;
    float*          x1     = (float*)(w);                      // 38,400,000
    unsigned short* y0     = (unsigned short*)(w + 38400000);  // 19,200,000
    unsigned short* y1     = (unsigned short*)(w + 57600000);  // 19,200,000
    int*            csv    = (int*)(w + 76800000);             // 12,000,000
    int2*           roff   = (int2*)(w + 88800000);            //  2,400,000
    unsigned short* e16    = (unsigned short*)(w + 91200000);  //  4,800,000
    unsigned int*   stage  = (unsigned int*)(w + 96000000);    // 12,000,000
    int*            cnt    = (int*)(w + 108000000);            //    860,248
    int*            exsc   = (int*)(w + 108860248);            //    860,248
    int*            tot    = (int*)(w + 109720496);            //      2,344
    int*            bstart = (int*)(w + 109722840);            //      2,348
    // total ~109.7 MB

    const int gRows = NN / 4;                    // 37,500

    // deterministic CSR build for both layers (zero global atomics)
    k_pcount<<<2 * NCHUNK, 256, 0, stream>>>(idx, cnt);
    k_bukscan<<<NB, 512, 0, stream>>>(cnt, exsc, tot);
    k_totscan<<<1, 1024, 0, stream>>>(tot, bstart);
    k_pscatter<<<2 * NCHUNK, 256, 0, stream>>>(idx, ptyp, exsc, bstart, stage);
    k_bscatter<<<NB, 1024, 0, stream>>>(stage, bstart, csv, roff);

    // eigs -> bf16, layer-0 LN
    k_eig<<<(NN * DE + 255) / 256, 256, 0, stream>>>(eigs, e16);
    k_ln0<<<gRows, 256, 0, stream>>>(uemb, iemb, y0);

    // layer 0: writes x1 + y1=LN(x1)
    k_row<<<gRows, 256, 0, stream>>>(y0, e16, roff, csv, pw, lam, 0,
                                     nullptr, nullptr, x1, y1, nullptr);
    // layer 1: writes final output (emb + x1 + x2)/3
    k_row<<<gRows, 256, 0, stream>>>(y1, e16, roff + NN, csv, pw, lam, 1,
                                     uemb, iemb, x1, nullptr, (float*)d_out);
}